// Round 8
// baseline (794.738 us; speedup 1.0000x reference)
//
#include <hip/hip_runtime.h>
#include <hip/hip_bf16.h>

// GCN: 3x GCNConv(relu) + mean-pool + linear + log_softmax
// N=100000 nodes, E=1600000 edges, F=128 -> 64 -> 64 -> 64, 256 graphs, 15 classes.
//
// Round 8 structure:
//  - norm folded into gather table: xwb[i] = bf16(dinv[i] * (h@W)[i])
//  - CSR build via 2-pass bucket sort (random 8B scatter measured 120-135us =
//    line-amplified writeback 1.6M x 64B = 102MB @ ~0.9TB/s; fix = locality):
//      pass1: stage edges bucket-major (bucket = 128-node range, offsets free
//             from rowptr[b<<7]); adjacent atomic tickets -> L2 line merge
//      pass2: stream stage, finalize col[] within each bucket's 8KB CSR window
//  - separate gemm + agg kernels (fusion measured slower in r5)

#define N_GRAPHS 256
#define HIDDEN 64
#define N_CLASSES 15
#define TILE_ROWS 32
#define SCAN_CHUNK 1024   // per block: 256 threads x 4 elements
#define BSHIFT 7          // bucket = 128 consecutive nodes

__device__ __forceinline__ float bf2f(ushort u) {
    return __uint_as_float(((unsigned int)u) << 16);
}
__device__ __forceinline__ ushort f2bf(float f) {
    __hip_bfloat16 h = __float2bfloat16(f);  // RNE
    return *reinterpret_cast<ushort*>(&h);
}

// ---------------- degree histogram ----------------
__global__ void hist_kernel(const int* __restrict__ dst, int* __restrict__ deg, int E) {
    for (int e = blockIdx.x * blockDim.x + threadIdx.x; e < E; e += gridDim.x * blockDim.x) {
        atomicAdd(&deg[dst[e]], 1);
    }
}

// ---------------- 3-phase device-wide exclusive scan of deg -> rowptr ----------------
__global__ __launch_bounds__(256) void scan_a_kernel(const int* __restrict__ deg,
                                                     int* __restrict__ bsum, int n) {
    int base = blockIdx.x * SCAN_CHUNK + threadIdx.x * 4;
    int s = 0;
#pragma unroll
    for (int j = 0; j < 4; ++j) {
        int i = base + j;
        if (i < n) s += deg[i];
    }
    __shared__ int ls[256];
    ls[threadIdx.x] = s;
    __syncthreads();
    for (int off = 128; off > 0; off >>= 1) {
        if (threadIdx.x < off) ls[threadIdx.x] += ls[threadIdx.x + off];
        __syncthreads();
    }
    if (threadIdx.x == 0) bsum[blockIdx.x] = ls[0];
}

__global__ __launch_bounds__(256) void scan_b_kernel(const int* __restrict__ bsum,
                                                     int* __restrict__ boff,
                                                     int* __restrict__ rowptr, int nb, int n) {
    __shared__ int s[256];
    int t = threadIdx.x;
    s[t] = (t < nb) ? bsum[t] : 0;
    __syncthreads();
    for (int off = 1; off < 256; off <<= 1) {
        int v = (t >= off) ? s[t - off] : 0;
        __syncthreads();
        s[t] += v;
        __syncthreads();
    }
    if (t < nb) boff[t] = (t == 0) ? 0 : s[t - 1];
    if (t == 0) rowptr[n] = s[255];
}

// per-block exclusive scan + offset -> rowptr; fused dinv = rsqrt(deg+1)
__global__ __launch_bounds__(256) void scan_c_kernel(const int* __restrict__ deg,
                                                     const int* __restrict__ boff,
                                                     int* __restrict__ rowptr,
                                                     float* __restrict__ dinv, int n) {
    int base = blockIdx.x * SCAN_CHUNK + threadIdx.x * 4;
    int v[4];
    int s = 0;
#pragma unroll
    for (int j = 0; j < 4; ++j) {
        int i = base + j;
        v[j] = (i < n) ? deg[i] : 0;
        s += v[j];
    }
    __shared__ int ls[256];
    ls[threadIdx.x] = s;
    __syncthreads();
    for (int off = 1; off < 256; off <<= 1) {
        int u = (threadIdx.x >= off) ? ls[threadIdx.x - off] : 0;
        __syncthreads();
        ls[threadIdx.x] += u;
        __syncthreads();
    }
    int run = boff[blockIdx.x] + ((threadIdx.x == 0) ? 0 : ls[threadIdx.x - 1]);
#pragma unroll
    for (int j = 0; j < 4; ++j) {
        int i = base + j;
        if (i < n) {
            rowptr[i] = run;
            dinv[i] = rsqrtf((float)(v[j] + 1));  // +1 = self-loop
            run += v[j];
        }
    }
}

// ---------------- pass 1: stage edges bucket-major ----------------
// bucket b = d>>7 covers nodes [b<<7, (b+1)<<7); its staging region starts at
// rowptr[b<<7] (free from the node scan). Adjacent atomic tickets within a
// bucket -> adjacent 8B stores -> L2 line merging (vs 102MB random writeback).
__global__ void stage_kernel(const int* __restrict__ src, const int* __restrict__ dst,
                             const int* __restrict__ rowptr, int* __restrict__ bfill,
                             int2* __restrict__ stage, int E) {
    for (int e = blockIdx.x * blockDim.x + threadIdx.x; e < E; e += gridDim.x * blockDim.x) {
        int d = dst[e], s = src[e];
        int pos = rowptr[d & ~((1 << BSHIFT) - 1)] + atomicAdd(&bfill[d >> BSHIFT], 1);
        stage[pos] = make_int2(s, d);
    }
}

// ---------------- pass 2: finalize CSR within each bucket's window ----------------
__global__ void scatter_final_kernel(const int2* __restrict__ stage,
                                     const int* __restrict__ rowptr, int* __restrict__ fill,
                                     int* __restrict__ col, int E) {
    for (int e = blockIdx.x * blockDim.x + threadIdx.x; e < E; e += gridDim.x * blockDim.x) {
        int2 sd = stage[e];
        int pos = rowptr[sd.y] + atomicAdd(&fill[sd.y], 1);
        col[pos] = sd.x;
    }
}

// ---------------- GEMM: XWB(bf16) = dinv .* (X @ W), tiled ----------------
// block = 256 threads (4 waves). One 32-row tile per block, grid-stride.
template <int FIN, typename TIN>
__global__ __launch_bounds__(256) void gemm_tile_kernel(const TIN* __restrict__ X,
                                                        const float* __restrict__ W,
                                                        const float* __restrict__ dinv,
                                                        ushort* __restrict__ XWB, int n) {
    __shared__ float xt[TILE_ROWS][FIN];
    __shared__ float wl[FIN * 64];
    for (int i = threadIdx.x; i < FIN * 64; i += 256) wl[i] = W[i];

    int lane = threadIdx.x & 63;
    int w = threadIdx.x >> 6;
    int ntiles = (n + TILE_ROWS - 1) / TILE_ROWS;

    for (int t = blockIdx.x; t < ntiles; t += gridDim.x) {
        int row0 = t * TILE_ROWS;
        __syncthreads();  // xt reuse guard (also covers initial wl stage)
        if constexpr (sizeof(TIN) == 4) {
            const int NF4 = TILE_ROWS * FIN / 4;  // float4 chunks
            for (int i = threadIdx.x; i < NF4; i += 256) {
                int r = i / (FIN / 4), k4 = i % (FIN / 4);
                int row = row0 + r;
                float4 v;
                if (row < n) v = *reinterpret_cast<const float4*>((const float*)X + (size_t)row * FIN + k4 * 4);
                else v = make_float4(0.f, 0.f, 0.f, 0.f);
                *reinterpret_cast<float4*>(&xt[r][k4 * 4]) = v;
            }
        } else {
            const int NC8 = TILE_ROWS * FIN / 8;  // 8 bf16 = 16B chunks
            for (int i = threadIdx.x; i < NC8; i += 256) {
                int r = i / (FIN / 8), k8 = i % (FIN / 8);
                int row = row0 + r;
                uint4 v = make_uint4(0u, 0u, 0u, 0u);
                if (row < n) v = *reinterpret_cast<const uint4*>((const ushort*)X + (size_t)row * FIN + k8 * 8);
                float* dstp = &xt[r][k8 * 8];
                dstp[0] = bf2f((ushort)(v.x & 0xffff));
                dstp[1] = bf2f((ushort)(v.x >> 16));
                dstp[2] = bf2f((ushort)(v.y & 0xffff));
                dstp[3] = bf2f((ushort)(v.y >> 16));
                dstp[4] = bf2f((ushort)(v.z & 0xffff));
                dstp[5] = bf2f((ushort)(v.z >> 16));
                dstp[6] = bf2f((ushort)(v.w & 0xffff));
                dstp[7] = bf2f((ushort)(v.w >> 16));
            }
        }
        __syncthreads();

        int r0 = w * 8;
        float acc[8] = {0.f, 0.f, 0.f, 0.f, 0.f, 0.f, 0.f, 0.f};
#pragma unroll 8
        for (int k = 0; k < FIN; ++k) {
            float wv = wl[k * 64 + lane];
#pragma unroll
            for (int j = 0; j < 8; ++j) acc[j] += xt[r0 + j][k] * wv;
        }
#pragma unroll
        for (int j = 0; j < 8; ++j) {
            int row = row0 + r0 + j;
            if (row < n) XWB[(size_t)row * 64 + lane] = f2bf(dinv[row] * acc[j]);
        }
    }
}

// ---------------- CSR aggregation: h = relu(dinv[i]*(xwb[i] + sum xwb[col]) + b), bf16 out ----------------
__global__ __launch_bounds__(256) void agg_csr_kernel(const ushort* __restrict__ XWB,
                                                      const int* __restrict__ rowptr,
                                                      const int* __restrict__ col,
                                                      const float* __restrict__ dinv,
                                                      const float* __restrict__ bias,
                                                      ushort* __restrict__ OUT, int n) {
    int lane = threadIdx.x & 63;
    int wid = (blockIdx.x * blockDim.x + threadIdx.x) >> 6;
    int nw = (gridDim.x * blockDim.x) >> 6;
    float b = bias[lane];
    for (int i = wid; i < n; i += nw) {
        float a0 = bf2f(XWB[(size_t)i * 64 + lane]);  // self-loop (pre-scaled)
        float a1 = 0.f, a2 = 0.f, a3 = 0.f, a4 = 0.f, a5 = 0.f, a6 = 0.f, a7 = 0.f;
        int p0 = __builtin_amdgcn_readfirstlane(rowptr[i]);
        int p1 = __builtin_amdgcn_readfirstlane(rowptr[i + 1]);
        int p = p0;
        for (; p + 8 <= p1; p += 8) {
            int c0 = col[p], c1 = col[p + 1], c2 = col[p + 2], c3 = col[p + 3];
            int c4 = col[p + 4], c5 = col[p + 5], c6 = col[p + 6], c7 = col[p + 7];
            a0 += bf2f(XWB[(size_t)c0 * 64 + lane]);
            a1 += bf2f(XWB[(size_t)c1 * 64 + lane]);
            a2 += bf2f(XWB[(size_t)c2 * 64 + lane]);
            a3 += bf2f(XWB[(size_t)c3 * 64 + lane]);
            a4 += bf2f(XWB[(size_t)c4 * 64 + lane]);
            a5 += bf2f(XWB[(size_t)c5 * 64 + lane]);
            a6 += bf2f(XWB[(size_t)c6 * 64 + lane]);
            a7 += bf2f(XWB[(size_t)c7 * 64 + lane]);
        }
        for (; p < p1; ++p) {
            a0 += bf2f(XWB[(size_t)col[p] * 64 + lane]);
        }
        float sum = ((a0 + a1) + (a2 + a3)) + ((a4 + a5) + (a6 + a7));
        float acc = dinv[i] * sum + b;
        OUT[(size_t)i * 64 + lane] = f2bf(fmaxf(acc, 0.f));
    }
}

// ---------------- mean pool (batch is sorted; H is bf16) ----------------
__global__ void pool_kernel(const ushort* __restrict__ H, const int* __restrict__ batch,
                            float* __restrict__ pooled, int n) {
    int g = blockIdx.x;
    int lo = 0, hi = n;
    while (lo < hi) { int mid = (lo + hi) >> 1; if (batch[mid] < g) lo = mid + 1; else hi = mid; }
    int start = lo;
    lo = 0; hi = n;
    while (lo < hi) { int mid = (lo + hi) >> 1; if (batch[mid] < g + 1) lo = mid + 1; else hi = mid; }
    int end = lo;

    int lane = threadIdx.x & 63;
    int w = threadIdx.x >> 6;
    __shared__ float part[4][64];
    float acc = 0.f;
    for (int i = start + w; i < end; i += 4) acc += bf2f(H[(size_t)i * 64 + lane]);
    part[w][lane] = acc;
    __syncthreads();
    if (w == 0) {
        float s = part[0][lane] + part[1][lane] + part[2][lane] + part[3][lane];
        float cnt = (float)(end - start);
        pooled[g * 64 + lane] = s / fmaxf(cnt, 1.0f);
    }
}

// ---------------- head ----------------
__global__ void head_kernel(const float* __restrict__ pooled, const float* __restrict__ fcw,
                            const float* __restrict__ fcb, float* __restrict__ out) {
    __shared__ float w[64 * N_CLASSES];
    __shared__ float bb[N_CLASSES];
    for (int i = threadIdx.x; i < 64 * N_CLASSES; i += blockDim.x) w[i] = fcw[i];
    if (threadIdx.x < N_CLASSES) bb[threadIdx.x] = fcb[threadIdx.x];
    __syncthreads();
    int g = threadIdx.x;  // 256 threads, one per graph
    float logits[N_CLASSES];
    float m = -1e30f;
    const float* pr = pooled + g * 64;
    for (int c = 0; c < N_CLASSES; ++c) {
        float acc = bb[c];
        for (int k = 0; k < 64; ++k) acc += pr[k] * w[k * N_CLASSES + c];
        logits[c] = acc;
        m = fmaxf(m, acc);
    }
    float se = 0.f;
    for (int c = 0; c < N_CLASSES; ++c) se += expf(logits[c] - m);
    float lse = m + logf(se);
    for (int c = 0; c < N_CLASSES; ++c) out[g * N_CLASSES + c] = logits[c] - lse;
}

extern "C" void kernel_launch(void* const* d_in, const int* in_sizes, int n_in,
                              void* d_out, int out_size, void* d_ws, size_t ws_size,
                              hipStream_t stream) {
    const float* x    = (const float*)d_in[0];
    const float* w1   = (const float*)d_in[1];
    const float* b1   = (const float*)d_in[2];
    const float* w2   = (const float*)d_in[3];
    const float* b2   = (const float*)d_in[4];
    const float* w3   = (const float*)d_in[5];
    const float* b3   = (const float*)d_in[6];
    const float* fcw  = (const float*)d_in[7];
    const float* fcb  = (const float*)d_in[8];
    const int*   ei   = (const int*)d_in[9];
    const int*   batch = (const int*)d_in[10];

    const int N = in_sizes[10];       // 100000
    const int E = in_sizes[9] / 2;    // 1600000
    const int* src = ei;
    const int* dst = ei + E;
    const int NBUCKETS = (N + (1 << BSHIFT) - 1) >> BSHIFT;  // 782

    char* ws = (char*)d_ws;
    size_t off = 0;
    auto alloc = [&](size_t bytes) -> void* {
        void* p = ws + off;
        off += (bytes + 255) & ~(size_t)255;
        return p;
    };
    int*    deg    = (int*)alloc((size_t)N * 4);
    int*    rowptr = (int*)alloc(((size_t)N + 1) * 4);
    int*    fill   = (int*)alloc((size_t)N * 4);
    int*    bfill  = (int*)alloc((size_t)NBUCKETS * 4);
    int2*   stage  = (int2*)alloc((size_t)E * 8);
    int*    col    = (int*)alloc((size_t)E * 4);
    float*  dinv   = (float*)alloc((size_t)N * 4);
    ushort* xwb    = (ushort*)alloc((size_t)N * 64 * 2);  // bf16 pre-scaled gather table
    ushort* hbuf   = (ushort*)alloc((size_t)N * 64 * 2);  // bf16 h
    float*  pooled = (float*)alloc((size_t)N_GRAPHS * 64 * 4);
    int*    bsum   = (int*)alloc(256 * 4);
    int*    boff   = (int*)alloc(256 * 4);
    (void)ws_size;

    hipMemsetAsync(deg, 0, (size_t)N * 4, stream);
    hipMemsetAsync(fill, 0, (size_t)N * 4, stream);
    hipMemsetAsync(bfill, 0, (size_t)NBUCKETS * 4, stream);

    const int GB = 2048;
    const int nb = (N + SCAN_CHUNK - 1) / SCAN_CHUNK;  // 98 blocks

    hist_kernel<<<GB, 256, 0, stream>>>(dst, deg, E);
    scan_a_kernel<<<nb, 256, 0, stream>>>(deg, bsum, N);
    scan_b_kernel<<<1, 256, 0, stream>>>(bsum, boff, rowptr, nb, N);
    scan_c_kernel<<<nb, 256, 0, stream>>>(deg, boff, rowptr, dinv, N);
    stage_kernel<<<GB, 256, 0, stream>>>(src, dst, rowptr, bfill, stage, E);
    scatter_final_kernel<<<GB, 256, 0, stream>>>(stage, rowptr, fill, col, E);

    int ntiles = (N + TILE_ROWS - 1) / TILE_ROWS;  // 3125

    // layer 1
    gemm_tile_kernel<128, float><<<ntiles, 256, 0, stream>>>(x, w1, dinv, xwb, N);
    agg_csr_kernel<<<GB, 256, 0, stream>>>(xwb, rowptr, col, dinv, b1, hbuf, N);
    // layer 2
    gemm_tile_kernel<64, ushort><<<ntiles, 256, 0, stream>>>(hbuf, w2, dinv, xwb, N);
    agg_csr_kernel<<<GB, 256, 0, stream>>>(xwb, rowptr, col, dinv, b2, hbuf, N);
    // layer 3
    gemm_tile_kernel<64, ushort><<<ntiles, 256, 0, stream>>>(hbuf, w3, dinv, xwb, N);
    agg_csr_kernel<<<GB, 256, 0, stream>>>(xwb, rowptr, col, dinv, b3, hbuf, N);

    pool_kernel<<<N_GRAPHS, 256, 0, stream>>>(hbuf, batch, pooled, N);
    head_kernel<<<1, 256, 0, stream>>>(pooled, fcw, fcb, (float*)d_out);
}

// Round 9
// 435.640 us; speedup vs baseline: 1.8243x; 1.8243x over previous
//
#include <hip/hip_runtime.h>
#include <hip/hip_bf16.h>

// GCN: 3x GCNConv(relu) + mean-pool + linear + log_softmax
// N=100000 nodes, E=1600000 edges, F=128 -> 64 -> 64 -> 64, 256 graphs, 15 classes.
//
// Round 9 structure:
//  - norm folded into gather table: xwb[i] = bf16(dinv[i] * (h@W)[i])
//  - CSR build = contention-free radix-style bucket sort:
//      measured constraints: random 4-8B stores cost ~120us (64B line amplification,
//      ~102MB writeback); same-address global atomics serialize at ~185ns (r8: 782
//      counters -> 378us). Fix: per-(block,bucket) LDS histogram -> offset matrix
//      scan (no atomics) -> placement with LDS tickets (stage runs ~168B, merge)
//      -> final scatter within L2-hot 32KB bucket windows.
//  - separate gemm + agg kernels (fusion measured slower in r5)

#define N_GRAPHS 256
#define HIDDEN 64
#define N_CLASSES 15
#define TILE_ROWS 32
#define SCAN_CHUNK 1024   // node-scan: per block 256 threads x 4 elements
#define NB_SHIFT 9        // bucket = 512 consecutive nodes
#define MAXNB 256         // supports N <= 131072
#define EDGE_CHUNK 4096   // edges per block in hist/place (16 per thread)

__device__ __forceinline__ float bf2f(ushort u) {
    return __uint_as_float(((unsigned int)u) << 16);
}
__device__ __forceinline__ ushort f2bf(float f) {
    __hip_bfloat16 h = __float2bfloat16(f);  // RNE
    return *reinterpret_cast<ushort*>(&h);
}

// ---------------- hist + per-(block,bucket) counts ----------------
__global__ __launch_bounds__(256) void hist_cnt_kernel(const int* __restrict__ dst,
                                                       int* __restrict__ deg,
                                                       int* __restrict__ cnt,
                                                       int E, int nblk) {
    __shared__ int lcnt[MAXNB];
    int blk = blockIdx.x;
    for (int i = threadIdx.x; i < MAXNB; i += 256) lcnt[i] = 0;
    __syncthreads();
    int base = blk * EDGE_CHUNK;
#pragma unroll
    for (int it = 0; it < EDGE_CHUNK / 256; ++it) {
        int e = base + it * 256 + threadIdx.x;
        if (e < E) {
            int d = dst[e];
            atomicAdd(&deg[d], 1);            // 100k addresses: low contention
            atomicAdd(&lcnt[d >> NB_SHIFT], 1);  // LDS
        }
    }
    __syncthreads();
    for (int b = threadIdx.x; b < MAXNB; b += 256) cnt[b * nblk + blk] = lcnt[b];
}

// ---------------- 3-phase device-wide exclusive scan of deg -> rowptr ----------------
__global__ __launch_bounds__(256) void scan_a_kernel(const int* __restrict__ deg,
                                                     int* __restrict__ bsum, int n) {
    int base = blockIdx.x * SCAN_CHUNK + threadIdx.x * 4;
    int s = 0;
#pragma unroll
    for (int j = 0; j < 4; ++j) {
        int i = base + j;
        if (i < n) s += deg[i];
    }
    __shared__ int ls[256];
    ls[threadIdx.x] = s;
    __syncthreads();
    for (int off = 128; off > 0; off >>= 1) {
        if (threadIdx.x < off) ls[threadIdx.x] += ls[threadIdx.x + off];
        __syncthreads();
    }
    if (threadIdx.x == 0) bsum[blockIdx.x] = ls[0];
}

__global__ __launch_bounds__(256) void scan_b_kernel(const int* __restrict__ bsum,
                                                     int* __restrict__ boff,
                                                     int* __restrict__ rowptr, int nb, int n) {
    __shared__ int s[256];
    int t = threadIdx.x;
    s[t] = (t < nb) ? bsum[t] : 0;
    __syncthreads();
    for (int off = 1; off < 256; off <<= 1) {
        int v = (t >= off) ? s[t - off] : 0;
        __syncthreads();
        s[t] += v;
        __syncthreads();
    }
    if (t < nb) boff[t] = (t == 0) ? 0 : s[t - 1];
    if (t == 0) rowptr[n] = s[255];
}

// per-block exclusive scan + offset -> rowptr; fused dinv = rsqrt(deg+1)
__global__ __launch_bounds__(256) void scan_c_kernel(const int* __restrict__ deg,
                                                     const int* __restrict__ boff,
                                                     int* __restrict__ rowptr,
                                                     float* __restrict__ dinv, int n) {
    int base = blockIdx.x * SCAN_CHUNK + threadIdx.x * 4;
    int v[4];
    int s = 0;
#pragma unroll
    for (int j = 0; j < 4; ++j) {
        int i = base + j;
        v[j] = (i < n) ? deg[i] : 0;
        s += v[j];
    }
    __shared__ int ls[256];
    ls[threadIdx.x] = s;
    __syncthreads();
    for (int off = 1; off < 256; off <<= 1) {
        int u = (threadIdx.x >= off) ? ls[threadIdx.x - off] : 0;
        __syncthreads();
        ls[threadIdx.x] += u;
        __syncthreads();
    }
    int run = boff[blockIdx.x] + ((threadIdx.x == 0) ? 0 : ls[threadIdx.x - 1]);
#pragma unroll
    for (int j = 0; j < 4; ++j) {
        int i = base + j;
        if (i < n) {
            rowptr[i] = run;
            dinv[i] = rsqrtf((float)(v[j] + 1));  // +1 = self-loop
            run += v[j];
        }
    }
}

// ---------------- offset matrix: cbase[b][blk] = rowptr[b<<9] + excl_scan(cnt[b][:]) ----------------
__global__ __launch_bounds__(256) void bucket_scan_kernel(const int* __restrict__ cnt,
                                                          const int* __restrict__ rowptr,
                                                          int* __restrict__ cbase, int nblk) {
    int b = blockIdx.x;
    __shared__ int ls[256];
    int t = threadIdx.x;
    int chunk = (nblk + 255) / 256;
    int start = t * chunk;
    int end = start + chunk;
    if (end > nblk) end = nblk;
    int s = 0;
    for (int i = start; i < end; ++i) s += cnt[b * nblk + i];
    ls[t] = s;
    __syncthreads();
    for (int off = 1; off < 256; off <<= 1) {
        int v = (t >= off) ? ls[t - off] : 0;
        __syncthreads();
        ls[t] += v;
        __syncthreads();
    }
    int run = rowptr[b << NB_SHIFT] + ((t == 0) ? 0 : ls[t - 1]);
    for (int i = start; i < end; ++i) {
        cbase[b * nblk + i] = run;
        run += cnt[b * nblk + i];
    }
}

// ---------------- placement: LDS tickets, bucket-major staging ----------------
__global__ __launch_bounds__(256) void place_kernel(const int* __restrict__ src,
                                                    const int* __restrict__ dst,
                                                    const int* __restrict__ cbase,
                                                    int2* __restrict__ stage,
                                                    int E, int nblk, int nb) {
    __shared__ int lpos[MAXNB];
    int blk = blockIdx.x;
    for (int b = threadIdx.x; b < nb; b += 256) lpos[b] = cbase[b * nblk + blk];
    __syncthreads();
    int base = blk * EDGE_CHUNK;
#pragma unroll
    for (int it = 0; it < EDGE_CHUNK / 256; ++it) {
        int e = base + it * 256 + threadIdx.x;
        if (e < E) {
            int d = dst[e], s = src[e];
            int slot = atomicAdd(&lpos[d >> NB_SHIFT], 1);  // LDS ticket
            stage[slot] = make_int2(s, d);
        }
    }
}

// ---------------- final scatter: bucket-major stream -> CSR col (L2-hot windows) ----------------
__global__ void scatter_final_kernel(const int2* __restrict__ stage,
                                     const int* __restrict__ rowptr, int* __restrict__ fill,
                                     int* __restrict__ col, int E) {
    for (int e = blockIdx.x * blockDim.x + threadIdx.x; e < E; e += gridDim.x * blockDim.x) {
        int2 sd = stage[e];
        int pos = rowptr[sd.y] + atomicAdd(&fill[sd.y], 1);
        col[pos] = sd.x;
    }
}

// ---------------- GEMM: XWB(bf16) = dinv .* (X @ W), tiled ----------------
// block = 256 threads (4 waves). One 32-row tile per block, grid-stride.
template <int FIN, typename TIN>
__global__ __launch_bounds__(256) void gemm_tile_kernel(const TIN* __restrict__ X,
                                                        const float* __restrict__ W,
                                                        const float* __restrict__ dinv,
                                                        ushort* __restrict__ XWB, int n) {
    __shared__ float xt[TILE_ROWS][FIN];
    __shared__ float wl[FIN * 64];
    for (int i = threadIdx.x; i < FIN * 64; i += 256) wl[i] = W[i];

    int lane = threadIdx.x & 63;
    int w = threadIdx.x >> 6;
    int ntiles = (n + TILE_ROWS - 1) / TILE_ROWS;

    for (int t = blockIdx.x; t < ntiles; t += gridDim.x) {
        int row0 = t * TILE_ROWS;
        __syncthreads();  // xt reuse guard (also covers initial wl stage)
        if constexpr (sizeof(TIN) == 4) {
            const int NF4 = TILE_ROWS * FIN / 4;  // float4 chunks
            for (int i = threadIdx.x; i < NF4; i += 256) {
                int r = i / (FIN / 4), k4 = i % (FIN / 4);
                int row = row0 + r;
                float4 v;
                if (row < n) v = *reinterpret_cast<const float4*>((const float*)X + (size_t)row * FIN + k4 * 4);
                else v = make_float4(0.f, 0.f, 0.f, 0.f);
                *reinterpret_cast<float4*>(&xt[r][k4 * 4]) = v;
            }
        } else {
            const int NC8 = TILE_ROWS * FIN / 8;  // 8 bf16 = 16B chunks
            for (int i = threadIdx.x; i < NC8; i += 256) {
                int r = i / (FIN / 8), k8 = i % (FIN / 8);
                int row = row0 + r;
                uint4 v = make_uint4(0u, 0u, 0u, 0u);
                if (row < n) v = *reinterpret_cast<const uint4*>((const ushort*)X + (size_t)row * FIN + k8 * 8);
                float* dstp = &xt[r][k8 * 8];
                dstp[0] = bf2f((ushort)(v.x & 0xffff));
                dstp[1] = bf2f((ushort)(v.x >> 16));
                dstp[2] = bf2f((ushort)(v.y & 0xffff));
                dstp[3] = bf2f((ushort)(v.y >> 16));
                dstp[4] = bf2f((ushort)(v.z & 0xffff));
                dstp[5] = bf2f((ushort)(v.z >> 16));
                dstp[6] = bf2f((ushort)(v.w & 0xffff));
                dstp[7] = bf2f((ushort)(v.w >> 16));
            }
        }
        __syncthreads();

        int r0 = w * 8;
        float acc[8] = {0.f, 0.f, 0.f, 0.f, 0.f, 0.f, 0.f, 0.f};
#pragma unroll 8
        for (int k = 0; k < FIN; ++k) {
            float wv = wl[k * 64 + lane];
#pragma unroll
            for (int j = 0; j < 8; ++j) acc[j] += xt[r0 + j][k] * wv;
        }
#pragma unroll
        for (int j = 0; j < 8; ++j) {
            int row = row0 + r0 + j;
            if (row < n) XWB[(size_t)row * 64 + lane] = f2bf(dinv[row] * acc[j]);
        }
    }
}

// ---------------- CSR aggregation: h = relu(dinv[i]*(xwb[i] + sum xwb[col]) + b), bf16 out ----------------
__global__ __launch_bounds__(256) void agg_csr_kernel(const ushort* __restrict__ XWB,
                                                      const int* __restrict__ rowptr,
                                                      const int* __restrict__ col,
                                                      const float* __restrict__ dinv,
                                                      const float* __restrict__ bias,
                                                      ushort* __restrict__ OUT, int n) {
    int lane = threadIdx.x & 63;
    int wid = (blockIdx.x * blockDim.x + threadIdx.x) >> 6;
    int nw = (gridDim.x * blockDim.x) >> 6;
    float b = bias[lane];
    for (int i = wid; i < n; i += nw) {
        float a0 = bf2f(XWB[(size_t)i * 64 + lane]);  // self-loop (pre-scaled)
        float a1 = 0.f, a2 = 0.f, a3 = 0.f, a4 = 0.f, a5 = 0.f, a6 = 0.f, a7 = 0.f;
        int p0 = __builtin_amdgcn_readfirstlane(rowptr[i]);
        int p1 = __builtin_amdgcn_readfirstlane(rowptr[i + 1]);
        int p = p0;
        for (; p + 8 <= p1; p += 8) {
            int c0 = col[p], c1 = col[p + 1], c2 = col[p + 2], c3 = col[p + 3];
            int c4 = col[p + 4], c5 = col[p + 5], c6 = col[p + 6], c7 = col[p + 7];
            a0 += bf2f(XWB[(size_t)c0 * 64 + lane]);
            a1 += bf2f(XWB[(size_t)c1 * 64 + lane]);
            a2 += bf2f(XWB[(size_t)c2 * 64 + lane]);
            a3 += bf2f(XWB[(size_t)c3 * 64 + lane]);
            a4 += bf2f(XWB[(size_t)c4 * 64 + lane]);
            a5 += bf2f(XWB[(size_t)c5 * 64 + lane]);
            a6 += bf2f(XWB[(size_t)c6 * 64 + lane]);
            a7 += bf2f(XWB[(size_t)c7 * 64 + lane]);
        }
        for (; p < p1; ++p) {
            a0 += bf2f(XWB[(size_t)col[p] * 64 + lane]);
        }
        float sum = ((a0 + a1) + (a2 + a3)) + ((a4 + a5) + (a6 + a7));
        float acc = dinv[i] * sum + b;
        OUT[(size_t)i * 64 + lane] = f2bf(fmaxf(acc, 0.f));
    }
}

// ---------------- mean pool (batch is sorted; H is bf16) ----------------
__global__ void pool_kernel(const ushort* __restrict__ H, const int* __restrict__ batch,
                            float* __restrict__ pooled, int n) {
    int g = blockIdx.x;
    int lo = 0, hi = n;
    while (lo < hi) { int mid = (lo + hi) >> 1; if (batch[mid] < g) lo = mid + 1; else hi = mid; }
    int start = lo;
    lo = 0; hi = n;
    while (lo < hi) { int mid = (lo + hi) >> 1; if (batch[mid] < g + 1) lo = mid + 1; else hi = mid; }
    int end = lo;

    int lane = threadIdx.x & 63;
    int w = threadIdx.x >> 6;
    __shared__ float part[4][64];
    float acc = 0.f;
    for (int i = start + w; i < end; i += 4) acc += bf2f(H[(size_t)i * 64 + lane]);
    part[w][lane] = acc;
    __syncthreads();
    if (w == 0) {
        float s = part[0][lane] + part[1][lane] + part[2][lane] + part[3][lane];
        float cnt = (float)(end - start);
        pooled[g * 64 + lane] = s / fmaxf(cnt, 1.0f);
    }
}

// ---------------- head ----------------
__global__ void head_kernel(const float* __restrict__ pooled, const float* __restrict__ fcw,
                            const float* __restrict__ fcb, float* __restrict__ out) {
    __shared__ float w[64 * N_CLASSES];
    __shared__ float bb[N_CLASSES];
    for (int i = threadIdx.x; i < 64 * N_CLASSES; i += blockDim.x) w[i] = fcw[i];
    if (threadIdx.x < N_CLASSES) bb[threadIdx.x] = fcb[threadIdx.x];
    __syncthreads();
    int g = threadIdx.x;  // 256 threads, one per graph
    float logits[N_CLASSES];
    float m = -1e30f;
    const float* pr = pooled + g * 64;
    for (int c = 0; c < N_CLASSES; ++c) {
        float acc = bb[c];
        for (int k = 0; k < 64; ++k) acc += pr[k] * w[k * N_CLASSES + c];
        logits[c] = acc;
        m = fmaxf(m, acc);
    }
    float se = 0.f;
    for (int c = 0; c < N_CLASSES; ++c) se += expf(logits[c] - m);
    float lse = m + logf(se);
    for (int c = 0; c < N_CLASSES; ++c) out[g * N_CLASSES + c] = logits[c] - lse;
}

extern "C" void kernel_launch(void* const* d_in, const int* in_sizes, int n_in,
                              void* d_out, int out_size, void* d_ws, size_t ws_size,
                              hipStream_t stream) {
    const float* x    = (const float*)d_in[0];
    const float* w1   = (const float*)d_in[1];
    const float* b1   = (const float*)d_in[2];
    const float* w2   = (const float*)d_in[3];
    const float* b2   = (const float*)d_in[4];
    const float* w3   = (const float*)d_in[5];
    const float* b3   = (const float*)d_in[6];
    const float* fcw  = (const float*)d_in[7];
    const float* fcb  = (const float*)d_in[8];
    const int*   ei   = (const int*)d_in[9];
    const int*   batch = (const int*)d_in[10];

    const int N = in_sizes[10];       // 100000
    const int E = in_sizes[9] / 2;    // 1600000
    const int* src = ei;
    const int* dst = ei + E;

    const int NBUCKETS = (N + (1 << NB_SHIFT) - 1) >> NB_SHIFT;    // 196
    const int NBLK = (E + EDGE_CHUNK - 1) / EDGE_CHUNK;            // 391

    char* ws = (char*)d_ws;
    size_t off = 0;
    auto alloc = [&](size_t bytes) -> void* {
        void* p = ws + off;
        off += (bytes + 255) & ~(size_t)255;
        return p;
    };
    int*    deg    = (int*)alloc((size_t)N * 4);
    int*    rowptr = (int*)alloc(((size_t)N + 1) * 4);
    int*    fill   = (int*)alloc((size_t)N * 4);
    int*    cnt    = (int*)alloc((size_t)MAXNB * NBLK * 4);   // per-(bucket,block) counts
    int*    cbase  = (int*)alloc((size_t)MAXNB * NBLK * 4);   // per-(bucket,block) offsets
    int2*   stage  = (int2*)alloc((size_t)E * 8);
    int*    col    = (int*)alloc((size_t)E * 4);
    float*  dinv   = (float*)alloc((size_t)N * 4);
    ushort* xwb    = (ushort*)alloc((size_t)N * 64 * 2);  // bf16 pre-scaled gather table
    ushort* hbuf   = (ushort*)alloc((size_t)N * 64 * 2);  // bf16 h
    float*  pooled = (float*)alloc((size_t)N_GRAPHS * 64 * 4);
    int*    bsum   = (int*)alloc(256 * 4);
    int*    boff   = (int*)alloc(256 * 4);
    (void)ws_size;

    hipMemsetAsync(deg, 0, (size_t)N * 4, stream);
    hipMemsetAsync(fill, 0, (size_t)N * 4, stream);

    const int GB = 2048;
    const int nb = (N + SCAN_CHUNK - 1) / SCAN_CHUNK;  // 98 blocks

    hist_cnt_kernel<<<NBLK, 256, 0, stream>>>(dst, deg, cnt, E, NBLK);
    scan_a_kernel<<<nb, 256, 0, stream>>>(deg, bsum, N);
    scan_b_kernel<<<1, 256, 0, stream>>>(bsum, boff, rowptr, nb, N);
    scan_c_kernel<<<nb, 256, 0, stream>>>(deg, boff, rowptr, dinv, N);
    bucket_scan_kernel<<<NBUCKETS, 256, 0, stream>>>(cnt, rowptr, cbase, NBLK);
    place_kernel<<<NBLK, 256, 0, stream>>>(src, dst, cbase, stage, E, NBLK, NBUCKETS);
    scatter_final_kernel<<<GB, 256, 0, stream>>>(stage, rowptr, fill, col, E);

    int ntiles = (N + TILE_ROWS - 1) / TILE_ROWS;  // 3125

    // layer 1
    gemm_tile_kernel<128, float><<<ntiles, 256, 0, stream>>>(x, w1, dinv, xwb, N);
    agg_csr_kernel<<<GB, 256, 0, stream>>>(xwb, rowptr, col, dinv, b1, hbuf, N);
    // layer 2
    gemm_tile_kernel<64, ushort><<<ntiles, 256, 0, stream>>>(hbuf, w2, dinv, xwb, N);
    agg_csr_kernel<<<GB, 256, 0, stream>>>(xwb, rowptr, col, dinv, b2, hbuf, N);
    // layer 3
    gemm_tile_kernel<64, ushort><<<ntiles, 256, 0, stream>>>(hbuf, w3, dinv, xwb, N);
    agg_csr_kernel<<<GB, 256, 0, stream>>>(xwb, rowptr, col, dinv, b3, hbuf, N);

    pool_kernel<<<N_GRAPHS, 256, 0, stream>>>(hbuf, batch, pooled, N);
    head_kernel<<<1, 256, 0, stream>>>(pooled, fcw, fcb, (float*)d_out);
}

// Round 10
// 341.416 us; speedup vs baseline: 2.3278x; 1.2760x over previous
//
#include <hip/hip_runtime.h>
#include <hip/hip_bf16.h>

// GCN: 3x GCNConv(relu) + mean-pool + linear + log_softmax
// N=100000 nodes, E=1600000 edges, F=128 -> 64 -> 64 -> 64, 256 graphs, 15 classes.
//
// Round 10 structure: ZERO global atomics.
//  Measured constraints driving this design:
//   - random 4-8B stores/atomic-RMW cost ~64B-line/32B amplification (~0.85 TB/s eff.)
//   - same-address global atomics serialize at ~185ns (r8)
//   - per-node global atomics = 53MB random RMW traffic = 62us (r9 hist_cnt)
//  Build: cnt (LDS per-block-bucket hist) -> bucket totals -> tiny scan -> cbase
//         -> place (LDS tickets, bucket-major stage) -> finalize (per-bucket block:
//         LDS 512-node hist + local scan -> rowptr/dinv; LDS tickets -> col in own
//         contiguous 32KB window). No deg array, no node-scan, no memsets.
//  Layers: gemm (pre-scaled bf16 table) + agg (8-acc gather) separate (r5: fusion slower).

#define N_GRAPHS 256
#define HIDDEN 64
#define N_CLASSES 15
#define TILE_ROWS 32
#define NB_SHIFT 9        // bucket = 512 consecutive nodes
#define MAXNB 256         // supports N <= 131072
#define EDGE_CHUNK 4096   // edges per block in cnt/place (16 per thread)

__device__ __forceinline__ float bf2f(ushort u) {
    return __uint_as_float(((unsigned int)u) << 16);
}
__device__ __forceinline__ ushort f2bf(float f) {
    __hip_bfloat16 h = __float2bfloat16(f);  // RNE
    return *reinterpret_cast<ushort*>(&h);
}

// ---------------- per-(block,bucket) counts (LDS only) ----------------
__global__ __launch_bounds__(256) void cnt_kernel(const int* __restrict__ dst,
                                                  int* __restrict__ cnt, int E, int nblk) {
    __shared__ int lcnt[MAXNB];
    int blk = blockIdx.x;
    for (int i = threadIdx.x; i < MAXNB; i += 256) lcnt[i] = 0;
    __syncthreads();
    int base = blk * EDGE_CHUNK;
#pragma unroll
    for (int it = 0; it < EDGE_CHUNK / 256; ++it) {
        int e = base + it * 256 + threadIdx.x;
        if (e < E) atomicAdd(&lcnt[dst[e] >> NB_SHIFT], 1);
    }
    __syncthreads();
    for (int b = threadIdx.x; b < MAXNB; b += 256) cnt[b * nblk + blk] = lcnt[b];
}

// ---------------- bucket totals ----------------
__global__ __launch_bounds__(256) void btot_kernel(const int* __restrict__ cnt,
                                                   int* __restrict__ btot, int nblk) {
    int b = blockIdx.x;
    __shared__ int ls[256];
    int s = 0;
    for (int i = threadIdx.x; i < nblk; i += 256) s += cnt[b * nblk + i];
    ls[threadIdx.x] = s;
    __syncthreads();
    for (int off = 128; off > 0; off >>= 1) {
        if (threadIdx.x < off) ls[threadIdx.x] += ls[threadIdx.x + off];
        __syncthreads();
    }
    if (threadIdx.x == 0) btot[b] = ls[0];
}

// ---------------- tiny exclusive scan of bucket totals -> sbase[0..nb] ----------------
__global__ __launch_bounds__(256) void sscan_kernel(const int* __restrict__ btot,
                                                    int* __restrict__ sbase, int nb) {
    __shared__ int s[256];
    int t = threadIdx.x;
    s[t] = (t < nb) ? btot[t] : 0;
    __syncthreads();
    for (int off = 1; off < 256; off <<= 1) {
        int v = (t >= off) ? s[t - off] : 0;
        __syncthreads();
        s[t] += v;
        __syncthreads();
    }
    if (t < nb) sbase[t] = (t == 0) ? 0 : s[t - 1];
    if (t == 0) sbase[nb] = s[255];
}

// ---------------- cbase[b][blk] = sbase[b] + excl_scan_blk(cnt[b][:]) ----------------
__global__ __launch_bounds__(256) void cbase_kernel(const int* __restrict__ cnt,
                                                    const int* __restrict__ sbase,
                                                    int* __restrict__ cbase, int nblk) {
    int b = blockIdx.x;
    __shared__ int ls[256];
    int t = threadIdx.x;
    int chunk = (nblk + 255) / 256;
    int start = t * chunk;
    int end = start + chunk;
    if (end > nblk) end = nblk;
    int s = 0;
    for (int i = start; i < end; ++i) s += cnt[b * nblk + i];
    ls[t] = s;
    __syncthreads();
    for (int off = 1; off < 256; off <<= 1) {
        int v = (t >= off) ? ls[t - off] : 0;
        __syncthreads();
        ls[t] += v;
        __syncthreads();
    }
    int run = sbase[b] + ((t == 0) ? 0 : ls[t - 1]);
    for (int i = start; i < end; ++i) {
        cbase[b * nblk + i] = run;
        run += cnt[b * nblk + i];
    }
}

// ---------------- placement: LDS tickets, bucket-major staging ----------------
__global__ __launch_bounds__(256) void place_kernel(const int* __restrict__ src,
                                                    const int* __restrict__ dst,
                                                    const int* __restrict__ cbase,
                                                    int2* __restrict__ stage,
                                                    int E, int nblk, int nb) {
    __shared__ int lpos[MAXNB];
    int blk = blockIdx.x;
    for (int b = threadIdx.x; b < nb; b += 256) lpos[b] = cbase[b * nblk + blk];
    __syncthreads();
    int base = blk * EDGE_CHUNK;
#pragma unroll
    for (int it = 0; it < EDGE_CHUNK / 256; ++it) {
        int e = base + it * 256 + threadIdx.x;
        if (e < E) {
            int d = dst[e], s = src[e];
            int slot = atomicAdd(&lpos[d >> NB_SHIFT], 1);  // LDS ticket
            stage[slot] = make_int2(s, d);
        }
    }
}

// ---------------- finalize: per-bucket deg/rowptr/dinv + CSR col (all bucket-local) ----------------
__global__ __launch_bounds__(256) void finalize_kernel(const int2* __restrict__ stage,
                                                       const int* __restrict__ sbase,
                                                       int* __restrict__ rowptr,
                                                       float* __restrict__ dinv,
                                                       int* __restrict__ col, int n, int nb) {
    int b = blockIdx.x;
    int t = threadIdx.x;
    int node0 = b << NB_SHIFT;
    int lo = sbase[b], hi = sbase[b + 1];

    __shared__ int lcnt[1 << NB_SHIFT];
    __shared__ int lrow[1 << NB_SHIFT];
    __shared__ int ls[256];

    lcnt[t] = 0;
    lcnt[t + 256] = 0;
    __syncthreads();
    // pass 1: local degree histogram
    for (int e = lo + t; e < hi; e += 256) {
        atomicAdd(&lcnt[stage[e].y - node0], 1);
    }
    __syncthreads();
    // local exclusive scan over 512 counters (2 per thread)
    int c0 = lcnt[2 * t], c1 = lcnt[2 * t + 1];
    ls[t] = c0 + c1;
    __syncthreads();
    for (int off = 1; off < 256; off <<= 1) {
        int v = (t >= off) ? ls[t - off] : 0;
        __syncthreads();
        ls[t] += v;
        __syncthreads();
    }
    int bse = (t == 0) ? 0 : ls[t - 1];
    lrow[2 * t] = bse;
    lrow[2 * t + 1] = bse + c0;
    // rowptr / dinv
    int i0 = node0 + 2 * t;
    if (i0 < n) {
        rowptr[i0] = lo + bse;
        dinv[i0] = rsqrtf((float)(c0 + 1));  // +1 = self-loop
    }
    if (i0 + 1 < n) {
        rowptr[i0 + 1] = lo + bse + c0;
        dinv[i0 + 1] = rsqrtf((float)(c1 + 1));
    }
    if (b == nb - 1 && t == 0) rowptr[n] = hi;
    __syncthreads();
    // reset counters for ticketing
    lcnt[t] = 0;
    lcnt[t + 256] = 0;
    __syncthreads();
    // pass 2: place col within this bucket's contiguous window [lo, hi)
    for (int e = lo + t; e < hi; e += 256) {
        int2 sd = stage[e];
        int li = sd.y - node0;
        int k = atomicAdd(&lcnt[li], 1);  // LDS ticket
        col[lo + lrow[li] + k] = sd.x;
    }
}

// ---------------- GEMM: XWB(bf16) = dinv .* (X @ W), tiled ----------------
// block = 256 threads (4 waves). One 32-row tile per block, grid-stride.
template <int FIN, typename TIN>
__global__ __launch_bounds__(256) void gemm_tile_kernel(const TIN* __restrict__ X,
                                                        const float* __restrict__ W,
                                                        const float* __restrict__ dinv,
                                                        ushort* __restrict__ XWB, int n) {
    __shared__ float xt[TILE_ROWS][FIN];
    __shared__ float wl[FIN * 64];
    for (int i = threadIdx.x; i < FIN * 64; i += 256) wl[i] = W[i];

    int lane = threadIdx.x & 63;
    int w = threadIdx.x >> 6;
    int ntiles = (n + TILE_ROWS - 1) / TILE_ROWS;

    for (int t = blockIdx.x; t < ntiles; t += gridDim.x) {
        int row0 = t * TILE_ROWS;
        __syncthreads();  // xt reuse guard (also covers initial wl stage)
        if constexpr (sizeof(TIN) == 4) {
            const int NF4 = TILE_ROWS * FIN / 4;  // float4 chunks
            for (int i = threadIdx.x; i < NF4; i += 256) {
                int r = i / (FIN / 4), k4 = i % (FIN / 4);
                int row = row0 + r;
                float4 v;
                if (row < n) v = *reinterpret_cast<const float4*>((const float*)X + (size_t)row * FIN + k4 * 4);
                else v = make_float4(0.f, 0.f, 0.f, 0.f);
                *reinterpret_cast<float4*>(&xt[r][k4 * 4]) = v;
            }
        } else {
            const int NC8 = TILE_ROWS * FIN / 8;  // 8 bf16 = 16B chunks
            for (int i = threadIdx.x; i < NC8; i += 256) {
                int r = i / (FIN / 8), k8 = i % (FIN / 8);
                int row = row0 + r;
                uint4 v = make_uint4(0u, 0u, 0u, 0u);
                if (row < n) v = *reinterpret_cast<const uint4*>((const ushort*)X + (size_t)row * FIN + k8 * 8);
                float* dstp = &xt[r][k8 * 8];
                dstp[0] = bf2f((ushort)(v.x & 0xffff));
                dstp[1] = bf2f((ushort)(v.x >> 16));
                dstp[2] = bf2f((ushort)(v.y & 0xffff));
                dstp[3] = bf2f((ushort)(v.y >> 16));
                dstp[4] = bf2f((ushort)(v.z & 0xffff));
                dstp[5] = bf2f((ushort)(v.z >> 16));
                dstp[6] = bf2f((ushort)(v.w & 0xffff));
                dstp[7] = bf2f((ushort)(v.w >> 16));
            }
        }
        __syncthreads();

        int r0 = w * 8;
        float acc[8] = {0.f, 0.f, 0.f, 0.f, 0.f, 0.f, 0.f, 0.f};
#pragma unroll 8
        for (int k = 0; k < FIN; ++k) {
            float wv = wl[k * 64 + lane];
#pragma unroll
            for (int j = 0; j < 8; ++j) acc[j] += xt[r0 + j][k] * wv;
        }
#pragma unroll
        for (int j = 0; j < 8; ++j) {
            int row = row0 + r0 + j;
            if (row < n) XWB[(size_t)row * 64 + lane] = f2bf(dinv[row] * acc[j]);
        }
    }
}

// ---------------- CSR aggregation: h = relu(dinv[i]*(xwb[i] + sum xwb[col]) + b), bf16 out ----------------
__global__ __launch_bounds__(256) void agg_csr_kernel(const ushort* __restrict__ XWB,
                                                      const int* __restrict__ rowptr,
                                                      const int* __restrict__ col,
                                                      const float* __restrict__ dinv,
                                                      const float* __restrict__ bias,
                                                      ushort* __restrict__ OUT, int n) {
    int lane = threadIdx.x & 63;
    int wid = (blockIdx.x * blockDim.x + threadIdx.x) >> 6;
    int nw = (gridDim.x * blockDim.x) >> 6;
    float b = bias[lane];
    for (int i = wid; i < n; i += nw) {
        float a0 = bf2f(XWB[(size_t)i * 64 + lane]);  // self-loop (pre-scaled)
        float a1 = 0.f, a2 = 0.f, a3 = 0.f, a4 = 0.f, a5 = 0.f, a6 = 0.f, a7 = 0.f;
        int p0 = __builtin_amdgcn_readfirstlane(rowptr[i]);
        int p1 = __builtin_amdgcn_readfirstlane(rowptr[i + 1]);
        int p = p0;
        for (; p + 8 <= p1; p += 8) {
            int c0 = col[p], c1 = col[p + 1], c2 = col[p + 2], c3 = col[p + 3];
            int c4 = col[p + 4], c5 = col[p + 5], c6 = col[p + 6], c7 = col[p + 7];
            a0 += bf2f(XWB[(size_t)c0 * 64 + lane]);
            a1 += bf2f(XWB[(size_t)c1 * 64 + lane]);
            a2 += bf2f(XWB[(size_t)c2 * 64 + lane]);
            a3 += bf2f(XWB[(size_t)c3 * 64 + lane]);
            a4 += bf2f(XWB[(size_t)c4 * 64 + lane]);
            a5 += bf2f(XWB[(size_t)c5 * 64 + lane]);
            a6 += bf2f(XWB[(size_t)c6 * 64 + lane]);
            a7 += bf2f(XWB[(size_t)c7 * 64 + lane]);
        }
        for (; p < p1; ++p) {
            a0 += bf2f(XWB[(size_t)col[p] * 64 + lane]);
        }
        float sum = ((a0 + a1) + (a2 + a3)) + ((a4 + a5) + (a6 + a7));
        float acc = dinv[i] * sum + b;
        OUT[(size_t)i * 64 + lane] = f2bf(fmaxf(acc, 0.f));
    }
}

// ---------------- mean pool (batch is sorted; H is bf16) ----------------
__global__ void pool_kernel(const ushort* __restrict__ H, const int* __restrict__ batch,
                            float* __restrict__ pooled, int n) {
    int g = blockIdx.x;
    int lo = 0, hi = n;
    while (lo < hi) { int mid = (lo + hi) >> 1; if (batch[mid] < g) lo = mid + 1; else hi = mid; }
    int start = lo;
    lo = 0; hi = n;
    while (lo < hi) { int mid = (lo + hi) >> 1; if (batch[mid] < g + 1) lo = mid + 1; else hi = mid; }
    int end = lo;

    int lane = threadIdx.x & 63;
    int w = threadIdx.x >> 6;
    __shared__ float part[4][64];
    float acc = 0.f;
    for (int i = start + w; i < end; i += 4) acc += bf2f(H[(size_t)i * 64 + lane]);
    part[w][lane] = acc;
    __syncthreads();
    if (w == 0) {
        float s = part[0][lane] + part[1][lane] + part[2][lane] + part[3][lane];
        float cnt = (float)(end - start);
        pooled[g * 64 + lane] = s / fmaxf(cnt, 1.0f);
    }
}

// ---------------- head ----------------
__global__ void head_kernel(const float* __restrict__ pooled, const float* __restrict__ fcw,
                            const float* __restrict__ fcb, float* __restrict__ out) {
    __shared__ float w[64 * N_CLASSES];
    __shared__ float bb[N_CLASSES];
    for (int i = threadIdx.x; i < 64 * N_CLASSES; i += blockDim.x) w[i] = fcw[i];
    if (threadIdx.x < N_CLASSES) bb[threadIdx.x] = fcb[threadIdx.x];
    __syncthreads();
    int g = threadIdx.x;  // 256 threads, one per graph
    float logits[N_CLASSES];
    float m = -1e30f;
    const float* pr = pooled + g * 64;
    for (int c = 0; c < N_CLASSES; ++c) {
        float acc = bb[c];
        for (int k = 0; k < 64; ++k) acc += pr[k] * w[k * N_CLASSES + c];
        logits[c] = acc;
        m = fmaxf(m, acc);
    }
    float se = 0.f;
    for (int c = 0; c < N_CLASSES; ++c) se += expf(logits[c] - m);
    float lse = m + logf(se);
    for (int c = 0; c < N_CLASSES; ++c) out[g * N_CLASSES + c] = logits[c] - lse;
}

extern "C" void kernel_launch(void* const* d_in, const int* in_sizes, int n_in,
                              void* d_out, int out_size, void* d_ws, size_t ws_size,
                              hipStream_t stream) {
    const float* x    = (const float*)d_in[0];
    const float* w1   = (const float*)d_in[1];
    const float* b1   = (const float*)d_in[2];
    const float* w2   = (const float*)d_in[3];
    const float* b2   = (const float*)d_in[4];
    const float* w3   = (const float*)d_in[5];
    const float* b3   = (const float*)d_in[6];
    const float* fcw  = (const float*)d_in[7];
    const float* fcb  = (const float*)d_in[8];
    const int*   ei   = (const int*)d_in[9];
    const int*   batch = (const int*)d_in[10];

    const int N = in_sizes[10];       // 100000
    const int E = in_sizes[9] / 2;    // 1600000
    const int* src = ei;
    const int* dst = ei + E;

    const int NBUCK = (N + (1 << NB_SHIFT) - 1) >> NB_SHIFT;   // 196
    const int NBLK = (E + EDGE_CHUNK - 1) / EDGE_CHUNK;        // 391

    char* ws = (char*)d_ws;
    size_t off = 0;
    auto alloc = [&](size_t bytes) -> void* {
        void* p = ws + off;
        off += (bytes + 255) & ~(size_t)255;
        return p;
    };
    int*    rowptr = (int*)alloc(((size_t)N + 1) * 4);
    int*    cnt    = (int*)alloc((size_t)MAXNB * NBLK * 4);
    int*    cbase  = (int*)alloc((size_t)MAXNB * NBLK * 4);
    int*    btot   = (int*)alloc(256 * 4);
    int*    sbase  = (int*)alloc(260 * 4);
    int2*   stage  = (int2*)alloc((size_t)E * 8);
    int*    col    = (int*)alloc((size_t)E * 4);
    float*  dinv   = (float*)alloc((size_t)N * 4);
    ushort* xwb    = (ushort*)alloc((size_t)N * 64 * 2);  // bf16 pre-scaled gather table
    ushort* hbuf   = (ushort*)alloc((size_t)N * 64 * 2);  // bf16 h
    float*  pooled = (float*)alloc((size_t)N_GRAPHS * 64 * 4);
    (void)ws_size;

    const int GB = 2048;

    cnt_kernel<<<NBLK, 256, 0, stream>>>(dst, cnt, E, NBLK);
    btot_kernel<<<NBUCK, 256, 0, stream>>>(cnt, btot, NBLK);
    sscan_kernel<<<1, 256, 0, stream>>>(btot, sbase, NBUCK);
    cbase_kernel<<<NBUCK, 256, 0, stream>>>(cnt, sbase, cbase, NBLK);
    place_kernel<<<NBLK, 256, 0, stream>>>(src, dst, cbase, stage, E, NBLK, NBUCK);
    finalize_kernel<<<NBUCK, 256, 0, stream>>>(stage, sbase, rowptr, dinv, col, N, NBUCK);

    int ntiles = (N + TILE_ROWS - 1) / TILE_ROWS;  // 3125

    // layer 1
    gemm_tile_kernel<128, float><<<ntiles, 256, 0, stream>>>(x, w1, dinv, xwb, N);
    agg_csr_kernel<<<GB, 256, 0, stream>>>(xwb, rowptr, col, dinv, b1, hbuf, N);
    // layer 2
    gemm_tile_kernel<64, ushort><<<ntiles, 256, 0, stream>>>(hbuf, w2, dinv, xwb, N);
    agg_csr_kernel<<<GB, 256, 0, stream>>>(xwb, rowptr, col, dinv, b2, hbuf, N);
    // layer 3
    gemm_tile_kernel<64, ushort><<<ntiles, 256, 0, stream>>>(hbuf, w3, dinv, xwb, N);
    agg_csr_kernel<<<GB, 256, 0, stream>>>(xwb, rowptr, col, dinv, b3, hbuf, N);

    pool_kernel<<<N_GRAPHS, 256, 0, stream>>>(hbuf, batch, pooled, N);
    head_kernel<<<1, 256, 0, stream>>>(pooled, fcw, fcb, (float*)d_out);
}